// Round 8
// baseline (280.814 us; speedup 1.0000x reference)
//
#include <hip/hip_runtime.h>

// GCN 2-layer + edge MLP for SimpleModel_59545426592235.
// R8: deterministic two-level scan gives every (chunk,bucket) its exact
// output range -> k_part has ZERO global atomics and runs at CH=2048
// (1563 blocks, ~6 blocks/CU) so scattered-store latency is hidden.
// k_hist persists per-chunk histograms (ccnt); k_scanA column-scans ccnt
// in place (one block per bucket) + totals; k_scanB scans totals -> gbase.
// nodeA/B/C aggregation loops 8x unrolled for gather ILP. Packed-u64
// fixed-point LDS atomics as in R6/R7. Fully deterministic.

#define BLK 256
#define BSH 7              // 128 nodes per bucket
#define BSZ 128
#define NBMAX 1024         // max buckets (N <= 131072)
#define NBP 1024           // ccnt row stride (ints)
#define NCHMAX 2048        // max chunks
#define S1 262144.0f       // 2^18 conv1 scale
#define S2 65536.0f        // 2^16 conv2 scale
#define BIAS 8388608       // 2^23 low-field bias

// ---- per-chunk LDS histogram -> ccnt row (no global atomics)
__global__ void k_hist(const int* __restrict__ col, int* __restrict__ ccnt,
                       int E, int NB, int CH) {
    __shared__ int hist[NBMAX];
    int t = threadIdx.x;
    for (int b = t; b < NB; b += BLK) hist[b] = 0;
    __syncthreads();
    int e0 = blockIdx.x * CH;
    int cnt = min(CH, E - e0);
    int k = t;
    for (; k + 3 * BLK < cnt; k += 4 * BLK) {
        int c0 = col[e0 + k], c1 = col[e0 + k + BLK];
        int c2 = col[e0 + k + 2 * BLK], c3 = col[e0 + k + 3 * BLK];
        atomicAdd(&hist[c0 >> BSH], 1);
        atomicAdd(&hist[c1 >> BSH], 1);
        atomicAdd(&hist[c2 >> BSH], 1);
        atomicAdd(&hist[c3 >> BSH], 1);
    }
    for (; k < cnt; k += BLK)
        atomicAdd(&hist[col[e0 + k] >> BSH], 1);
    __syncthreads();
    int* crow = ccnt + (size_t)blockIdx.x * NBP;
    for (int b = t; b < NB; b += BLK) crow[b] = hist[b];
}

// ---- column-wise exclusive scan of ccnt (in place), totals -> gcount
__global__ void k_scanA(int* __restrict__ ccnt, int* __restrict__ gcount, int NCH) {
    __shared__ int sa[NCHMAX], sb[NCHMAX];
    int b = blockIdx.x;
    int t = threadIdx.x;
    for (int i = t; i < NCHMAX; i += BLK)
        sa[i] = (i < NCH) ? ccnt[(size_t)i * NBP + b] : 0;
    __syncthreads();
    int *src = sa, *dst = sb;
    for (int off = 1; off < NCHMAX; off <<= 1) {
        for (int i = t; i < NCHMAX; i += BLK)
            dst[i] = src[i] + ((i >= off) ? src[i - off] : 0);
        __syncthreads();
        int* tmp = src; src = dst; dst = tmp;
    }
    for (int i = t; i < NCH; i += BLK)
        ccnt[(size_t)i * NBP + b] = (i > 0) ? src[i - 1] : 0;  // exclusive
    if (t == 0) gcount[b] = src[NCH - 1];
}

// ---- exclusive scan of bucket totals -> gbase[NB+1]
__global__ void k_scanB(const int* __restrict__ gcount, int* __restrict__ gbase, int NB) {
    __shared__ int sa[NBMAX], sb[NBMAX];
    int t = threadIdx.x;
    for (int i = t; i < NBMAX; i += BLK) sa[i] = (i < NB) ? gcount[i] : 0;
    __syncthreads();
    int *src = sa, *dst = sb;
    for (int off = 1; off < NBMAX; off <<= 1) {
        for (int i = t; i < NBMAX; i += BLK)
            dst[i] = src[i] + ((i >= off) ? src[i - off] : 0);
        __syncthreads();
        int* tmp = src; src = dst; dst = tmp;
    }
    for (int i = t; i < NB; i += BLK)
        gbase[i] = (i > 0) ? src[i - 1] : 0;
    if (t == 0) gbase[NB] = src[NB - 1];
}

// ---- partition: exact precomputed bases, LDS cursor, direct scatter
__global__ void k_part(const int* __restrict__ row, const int* __restrict__ col,
                       const int* __restrict__ ccnt, const int* __restrict__ gbase,
                       unsigned* __restrict__ part, int E, int NB, int CH) {
    __shared__ int gb[NBMAX];
    int t = threadIdx.x;
    const int* crow = ccnt + (size_t)blockIdx.x * NBP;
    for (int b = t; b < NB; b += BLK) gb[b] = gbase[b] + crow[b];
    __syncthreads();
    int e0 = blockIdx.x * CH;
    int cnt = min(CH, E - e0);
    for (int k = t; k < cnt; k += BLK) {
        int e = e0 + k;
        int c = col[e];
        int b = c >> BSH;
        int off = atomicAdd(&gb[b], 1);
        part[off] = ((unsigned)row[e] << BSH) | (unsigned)(c & (BSZ - 1));
    }
}

// ---- per-bucket degree count -> deg, dinv, pi = x * dinv (fixed point)
__global__ void k_nodeA(const unsigned* __restrict__ part, const int* __restrict__ gbase,
                        const float2* __restrict__ x2, float* __restrict__ dinv,
                        int* __restrict__ degi, int2* __restrict__ pi, int N) {
    __shared__ int cnt[BSZ];
    int t = threadIdx.x;
    if (t < BSZ) cnt[t] = 0;
    __syncthreads();
    int b = blockIdx.x;
    int j0 = gbase[b], j1 = gbase[b + 1];
    int j = j0 + t;
    for (; j + 7 * BLK < j1; j += 8 * BLK) {
        unsigned w[8];
        #pragma unroll
        for (int u = 0; u < 8; u++) w[u] = part[j + u * BLK];
        #pragma unroll
        for (int u = 0; u < 8; u++) atomicAdd(&cnt[w[u] & (BSZ - 1)], 1);
    }
    for (; j < j1; j += BLK)
        atomicAdd(&cnt[part[j] & (BSZ - 1)], 1);
    __syncthreads();
    if (t < BSZ) {
        int node = (b << BSH) + t;
        if (node < N) {
            int dg = cnt[t];
            degi[node] = dg;
            float d = rsqrtf((float)(dg + 1));   // +1 self loop
            dinv[node] = d;
            float2 xv = x2[node];
            pi[node] = make_int2(__float2int_rn(xv.x * d * S1),
                                 __float2int_rn(xv.y * d * S1));
        }
    }
}

__device__ __forceinline__ unsigned long long pack64(int2 v) {
    return ((unsigned long long)(unsigned)v.x << 32) | (unsigned)(v.y + BIAS);
}

// ---- per-bucket conv1 aggregate (packed u64 LDS) -> h -> U, V, qi
__global__ void k_nodeB(const unsigned* __restrict__ part, const int* __restrict__ gbase,
                        const float* __restrict__ dinv, const int* __restrict__ degi,
                        const int2* __restrict__ pi,
                        const float* __restrict__ W1, const float* __restrict__ b1,
                        const float* __restrict__ W2, const float* __restrict__ We,
                        const float* __restrict__ be,
                        float4* __restrict__ U, float4* __restrict__ V,
                        int2* __restrict__ qi, int N) {
    __shared__ unsigned long long acc[BSZ];
    __shared__ float sW1[32], sb1[16], sW2[32], sWr[64], sWc[64], sbe[4];
    int t = threadIdx.x;
    if (t < BSZ) acc[t] = 0ull;
    if (t < 32) sW1[t] = W1[t];
    else if (t < 64) sW2[t - 32] = W2[t - 32];
    else if (t < 80) sb1[t - 64] = b1[t - 64];
    else if (t < 144) sWr[t - 80] = We[t - 80];          // We rows 0..15
    else if (t < 208) sWc[t - 144] = We[68 + (t - 144)]; // We rows 17..32
    else if (t < 212) sbe[t - 208] = be[t - 208];
    __syncthreads();
    int b = blockIdx.x;
    int j0 = gbase[b], j1 = gbase[b + 1];
    int j = j0 + t;
    for (; j + 7 * BLK < j1; j += 8 * BLK) {
        unsigned w[8];
        int2 p[8];
        #pragma unroll
        for (int u = 0; u < 8; u++) w[u] = part[j + u * BLK];
        #pragma unroll
        for (int u = 0; u < 8; u++) p[u] = pi[w[u] >> BSH];
        #pragma unroll
        for (int u = 0; u < 8; u++)
            atomicAdd(&acc[w[u] & (BSZ - 1)], pack64(p[u]));
    }
    for (; j < j1; j += BLK) {
        unsigned w = part[j];
        atomicAdd(&acc[w & (BSZ - 1)], pack64(pi[w >> BSH]));
    }
    __syncthreads();
    if (t < BSZ) {
        int node = (b << BSH) + t;
        if (node < N) {
            unsigned long long a = acc[t];
            int sx = (int)(unsigned)(a >> 32);
            long long sy = (long long)(unsigned)(a & 0xffffffffull)
                         - (long long)degi[node] * BIAS;
            int2 ps = pi[node];  // self loop
            float d = dinv[node];
            float ax = (float)(ps.x + (long long)sx) * (1.0f / S1);
            float ay = (float)(ps.y + sy) * (1.0f / S1);
            float s0 = d * ax, s1 = d * ay;
            float u0 = sbe[0], u1 = sbe[1], u2 = sbe[2], u3 = sbe[3];
            float v0 = 0.f, v1 = 0.f, v2 = 0.f, v3 = 0.f;
            float w0 = 0.f, w1 = 0.f;
            #pragma unroll
            for (int jj = 0; jj < 16; jj++) {
                float hj = fmaf(s0, sW1[jj], fmaf(s1, sW1[16 + jj], sb1[jj]));
                u0 = fmaf(hj, sWr[4 * jj + 0], u0);
                u1 = fmaf(hj, sWr[4 * jj + 1], u1);
                u2 = fmaf(hj, sWr[4 * jj + 2], u2);
                u3 = fmaf(hj, sWr[4 * jj + 3], u3);
                v0 = fmaf(hj, sWc[4 * jj + 0], v0);
                v1 = fmaf(hj, sWc[4 * jj + 1], v1);
                v2 = fmaf(hj, sWc[4 * jj + 2], v2);
                v3 = fmaf(hj, sWc[4 * jj + 3], v3);
                w0 = fmaf(hj, sW2[2 * jj], w0);
                w1 = fmaf(hj, sW2[2 * jj + 1], w1);
            }
            U[node] = make_float4(u0, u1, u2, u3);
            V[node] = make_float4(v0, v1, v2, v3);
            float qx = w0 * d, qy = w1 * d;
            qi[node] = make_int2(__float2int_rn(qx * S2), __float2int_rn(qy * S2));
        }
    }
}

// ---- edge MLP: pure streaming, no atomics
__global__ void k_edge(const int* __restrict__ row, const int* __restrict__ col,
                       const float* __restrict__ ea, const float4* __restrict__ U,
                       const float4* __restrict__ V, const float* __restrict__ We,
                       float4* __restrict__ eout, int E) {
    __shared__ float sW16[4];
    int t = threadIdx.x;
    if (t < 4) sW16[t] = We[64 + t];   // We row 16 (edge_attr weights)
    __syncthreads();
    int e = blockIdx.x * BLK + t;
    if (e < E) {
        float4 u = U[row[e]];
        float4 v = V[col[e]];
        float av = ea[e];
        float a0 = u.x + fmaf(av, sW16[0], v.x);
        float a1 = u.y + fmaf(av, sW16[1], v.y);
        float a2 = u.z + fmaf(av, sW16[2], v.z);
        float a3 = u.w + fmaf(av, sW16[3], v.w);
        a0 = fmaxf(a0, 0.f); a1 = fmaxf(a1, 0.f);
        a2 = fmaxf(a2, 0.f); a3 = fmaxf(a3, 0.f);
        float m = fmaxf(fmaxf(a0, a1), fmaxf(a2, a3));
        float s = expf(a0 - m) + expf(a1 - m) + expf(a2 - m) + expf(a3 - m);
        float l = m + logf(s);
        eout[e] = make_float4(a0 - l, a1 - l, a2 - l, a3 - l);
    }
}

// ---- per-bucket conv2 aggregate (packed u64 LDS) -> node log_softmax
__global__ void k_nodeC(const unsigned* __restrict__ part, const int* __restrict__ gbase,
                        const float* __restrict__ dinv, const int* __restrict__ degi,
                        const int2* __restrict__ qi,
                        const float* __restrict__ b2, float2* __restrict__ outn, int N) {
    __shared__ unsigned long long acc[BSZ];
    int t = threadIdx.x;
    if (t < BSZ) acc[t] = 0ull;
    __syncthreads();
    int b = blockIdx.x;
    int j0 = gbase[b], j1 = gbase[b + 1];
    int j = j0 + t;
    for (; j + 7 * BLK < j1; j += 8 * BLK) {
        unsigned w[8];
        int2 q[8];
        #pragma unroll
        for (int u = 0; u < 8; u++) w[u] = part[j + u * BLK];
        #pragma unroll
        for (int u = 0; u < 8; u++) q[u] = qi[w[u] >> BSH];
        #pragma unroll
        for (int u = 0; u < 8; u++)
            atomicAdd(&acc[w[u] & (BSZ - 1)], pack64(q[u]));
    }
    for (; j < j1; j += BLK) {
        unsigned w = part[j];
        atomicAdd(&acc[w & (BSZ - 1)], pack64(qi[w >> BSH]));
    }
    __syncthreads();
    if (t < BSZ) {
        int node = (b << BSH) + t;
        if (node < N) {
            unsigned long long a = acc[t];
            int sx = (int)(unsigned)(a >> 32);
            long long sy = (long long)(unsigned)(a & 0xffffffffull)
                         - (long long)degi[node] * BIAS;
            int2 qs = qi[node];  // self loop
            float d = dinv[node];
            float bx = (float)(qs.x + (long long)sx) * (1.0f / S2);
            float by = (float)(qs.y + sy) * (1.0f / S2);
            float o0 = fmaf(d, bx, b2[0]);
            float o1 = fmaf(d, by, b2[1]);
            float m = fmaxf(o0, o1);
            float l2 = m + logf(expf(o0 - m) + expf(o1 - m));
            outn[node] = make_float2(o0 - l2, o1 - l2);
        }
    }
}

extern "C" void kernel_launch(void* const* d_in, const int* in_sizes, int n_in,
                              void* d_out, int out_size, void* d_ws, size_t ws_size,
                              hipStream_t stream) {
    const float* x  = (const float*)d_in[0];
    const int*   ei = (const int*)d_in[1];
    const float* ea = (const float*)d_in[2];
    const float* W1 = (const float*)d_in[3];
    const float* b1 = (const float*)d_in[4];
    const float* We = (const float*)d_in[5];
    const float* be = (const float*)d_in[6];
    const float* W2 = (const float*)d_in[7];
    const float* b2 = (const float*)d_in[8];

    const int N = in_sizes[0] / 2;       // 100000
    const int E = in_sizes[2];           // 3200000
    const int* row = ei;
    const int* col = ei + E;
    const int NB = (N + BSZ - 1) >> BSH;    // 782 buckets

    float2* out_nodes = (float2*)d_out;                           // [N,2]
    float4* out_edges = (float4*)((float*)d_out + 2 * (size_t)N); // [E,4]

    // ws layout (bytes):
    char* ws = (char*)d_ws;
    int*      gcount  = (int*)     (ws + 0);         // NBMAX*4
    int*      gbase   = (int*)     (ws + 4096);      // (NBMAX+1)*4 (pad)
    float*    dinv    = (float*)   (ws + 16384);     // N*4
    int*      degi    = (int*)     (ws + 416384);    // N*4
    int2*     pi      = (int2*)    (ws + 816384);    // N*8
    int2*     qi      = (int2*)    (ws + 1616384);   // N*8
    float4*   U       = (float4*)  (ws + 2416384);   // N*16
    float4*   V       = (float4*)  (ws + 4016384);   // N*16
    unsigned* part    = (unsigned*)(ws + 5616384);   // E*4 = 12.8 MB
    int*      ccnt    = (int*)     (ws + 18416384);  // NCH*NBP*4

    // pick chunk size: prefer 2048 (more blocks) if ccnt fits in workspace
    int CH = 2048;
    int NCH = (E + CH - 1) / CH;
    if (18416384 + (size_t)NCH * NBP * 4 > ws_size) {
        CH = 4096;
        NCH = (E + CH - 1) / CH;
    }

    k_hist <<<NCH, BLK, 0, stream>>>(col, ccnt, E, NB, CH);
    k_scanA<<<NB,  BLK, 0, stream>>>(ccnt, gcount, NCH);
    k_scanB<<<1,   BLK, 0, stream>>>(gcount, gbase, NB);
    k_part <<<NCH, BLK, 0, stream>>>(row, col, ccnt, gbase, part, E, NB, CH);
    k_nodeA<<<NB,  BLK, 0, stream>>>(part, gbase, (const float2*)x, dinv, degi, pi, N);
    k_nodeB<<<NB,  BLK, 0, stream>>>(part, gbase, dinv, degi, pi, W1, b1, W2, We, be, U, V, qi, N);
    k_edge <<<(E + BLK - 1) / BLK, BLK, 0, stream>>>(row, col, ea, U, V, We, out_edges, E);
    k_nodeC<<<NB,  BLK, 0, stream>>>(part, gbase, dinv, degi, qi, b2, out_nodes, N);
}

// Round 9
// 272.537 us; speedup vs baseline: 1.0304x; 1.0304x over previous
//
#include <hip/hip_runtime.h>

// GCN 2-layer + edge MLP for SimpleModel_59545426592235.
// R9: partition into 196 super-buckets (512 nodes) -> ~10-edge runs cut the
// scattered-store write-amp ~4x vs 782 buckets (R8: WRITE 93MB, 7x). Then
// k_sort fully sorts each super-bucket segment by node IN LDS (in-place in
// `part`), computing deg/dinv/pi/rstart on the way. Aggregation (conv1 and
// conv2) becomes thread-per-node register accumulation over contiguous runs:
// ZERO atomics, no fixed point, deterministic. k_edge does 2 edges/thread.

#define BLK 256
#define CH 2048            // edges per chunk
#define SBH 9              // 512 nodes per super-bucket
#define SBS 512
#define NSBMAX 256         // max super-buckets (N <= 131072)
#define NCHMAX 2048        // max chunks (E <= 4.19M)
#define CAP 20480          // k_sort LDS segment capacity (words); E[seg]=16.3k, sigma~128

// ---- per-chunk LDS histogram of super-buckets -> ccnt row
__global__ void k_hist(const int* __restrict__ col, int* __restrict__ ccnt,
                       int E, int NSB) {
    __shared__ int hist[NSBMAX];
    int t = threadIdx.x;
    for (int b = t; b < NSB; b += BLK) hist[b] = 0;
    __syncthreads();
    int e0 = blockIdx.x * CH;
    int cnt = min(CH, E - e0);
    for (int k = t; k < cnt; k += BLK)
        atomicAdd(&hist[col[e0 + k] >> SBH], 1);
    __syncthreads();
    int* crow = ccnt + (size_t)blockIdx.x * NSBMAX;
    for (int b = t; b < NSB; b += BLK) crow[b] = hist[b];
}

// ---- column-wise exclusive scan of ccnt in place; totals -> gcount
__global__ void k_scanA(int* __restrict__ ccnt, int* __restrict__ gcount, int NCH) {
    __shared__ int sa[NCHMAX], sb[NCHMAX];
    int s = blockIdx.x, t = threadIdx.x;
    for (int i = t; i < NCHMAX; i += BLK)
        sa[i] = (i < NCH) ? ccnt[(size_t)i * NSBMAX + s] : 0;
    __syncthreads();
    int *src = sa, *dst = sb;
    for (int off = 1; off < NCHMAX; off <<= 1) {
        for (int i = t; i < NCHMAX; i += BLK)
            dst[i] = src[i] + ((i >= off) ? src[i - off] : 0);
        __syncthreads();
        int* tmp = src; src = dst; dst = tmp;
    }
    for (int i = t; i < NCH; i += BLK)
        ccnt[(size_t)i * NSBMAX + s] = (i > 0) ? src[i - 1] : 0;
    if (t == 0) gcount[s] = src[NCH - 1];
}

// ---- exclusive scan of super-bucket totals -> sbase[NSB+1]; rstart[N]=E
__global__ void k_scanB(const int* __restrict__ gcount, int* __restrict__ sbase,
                        int* __restrict__ rstart, int NSB, int N, int E) {
    __shared__ int sa[NSBMAX], sb[NSBMAX];
    int t = threadIdx.x;
    for (int i = t; i < NSBMAX; i += BLK) sa[i] = (i < NSB) ? gcount[i] : 0;
    __syncthreads();
    int *src = sa, *dst = sb;
    for (int off = 1; off < NSBMAX; off <<= 1) {
        for (int i = t; i < NSBMAX; i += BLK)
            dst[i] = src[i] + ((i >= off) ? src[i - off] : 0);
        __syncthreads();
        int* tmp = src; src = dst; dst = tmp;
    }
    for (int i = t; i < NSB; i += BLK)
        sbase[i] = (i > 0) ? src[i - 1] : 0;
    if (t == 0) { sbase[NSB] = src[NSB - 1]; rstart[N] = E; }
}

// ---- partition: exact bases (no global atomics), direct scatter
__global__ void k_part(const int* __restrict__ row, const int* __restrict__ col,
                       const int* __restrict__ ccnt, const int* __restrict__ sbase,
                       unsigned* __restrict__ part, int E, int NSB) {
    __shared__ int gb[NSBMAX];
    int t = threadIdx.x;
    const int* crow = ccnt + (size_t)blockIdx.x * NSBMAX;
    for (int b = t; b < NSB; b += BLK) gb[b] = sbase[b] + crow[b];
    __syncthreads();
    int e0 = blockIdx.x * CH;
    int cnt = min(CH, E - e0);
    for (int k = t; k < cnt; k += BLK) {
        int e = e0 + k;
        int c = col[e];
        int b = c >> SBH;
        int off = atomicAdd(&gb[b], 1);
        part[off] = ((unsigned)row[e] << SBH) | (unsigned)(c & (SBS - 1));
    }
}

// ---- per-super-bucket: full sort by local node (in LDS, in place in part),
//      plus deg -> dinv, pi = x*dinv, rstart
__global__ void __launch_bounds__(SBS) k_sort(unsigned* __restrict__ part,
                        const int* __restrict__ sbase, const float2* __restrict__ x2,
                        float* __restrict__ dinv, float2* __restrict__ pi,
                        int* __restrict__ rstart, int N) {
    __shared__ unsigned sbuf[CAP];
    __shared__ int cnt[SBS], sc[SBS], cur[SBS];
    int s = blockIdx.x, t = threadIdx.x;
    int j0 = sbase[s], j1 = sbase[s + 1];
    int m = j1 - j0;
    if (m > CAP) m = CAP;   // safety clamp (statistically unreachable)
    for (int k = t; k < m; k += SBS) sbuf[k] = part[j0 + k];
    cnt[t] = 0;
    __syncthreads();
    for (int k = t; k < m; k += SBS)
        atomicAdd(&cnt[sbuf[k] & (SBS - 1)], 1);
    __syncthreads();
    // inclusive scan of cnt -> sc
    sc[t] = cnt[t];
    __syncthreads();
    for (int off = 1; off < SBS; off <<= 1) {
        int v = sc[t];
        if (t >= off) v += sc[t - off];
        __syncthreads();
        sc[t] = v;
        __syncthreads();
    }
    int ex = sc[t] - cnt[t];   // exclusive prefix
    cur[t] = ex;
    int node = (s << SBH) + t;
    if (node < N) {
        int dg = cnt[t];
        float d = rsqrtf((float)(dg + 1));   // +1 self loop
        dinv[node] = d;
        float2 xv = x2[node];
        pi[node] = make_float2(xv.x * d, xv.y * d);
        rstart[node] = j0 + ex;
    }
    __syncthreads();
    for (int k = t; k < m; k += SBS) {
        unsigned w = sbuf[k];
        int dst = atomicAdd(&cur[w & (SBS - 1)], 1);
        part[j0 + dst] = w >> SBH;   // store row id, node-sorted
    }
}

// ---- conv1 aggregate: thread-per-node register sum over its run -> U,V,qv
__global__ void k_aggB(const unsigned* __restrict__ part, const int* __restrict__ rstart,
                       const float* __restrict__ dinv, const float2* __restrict__ pi,
                       const float* __restrict__ W1, const float* __restrict__ b1,
                       const float* __restrict__ W2, const float* __restrict__ We,
                       const float* __restrict__ be,
                       float4* __restrict__ U, float4* __restrict__ V,
                       float2* __restrict__ qv, int N) {
    __shared__ float sW1[32], sb1[16], sW2[32], sWr[64], sWc[64], sbe[4];
    int t = threadIdx.x;
    if (t < 32) sW1[t] = W1[t];
    else if (t < 64) sW2[t - 32] = W2[t - 32];
    else if (t < 80) sb1[t - 64] = b1[t - 64];
    else if (t < 144) sWr[t - 80] = We[t - 80];          // We rows 0..15
    else if (t < 208) sWc[t - 144] = We[68 + (t - 144)]; // We rows 17..32
    else if (t < 212) sbe[t - 208] = be[t - 208];
    __syncthreads();
    int n = blockIdx.x * BLK + t;
    if (n < N) {
        int r0 = rstart[n], r1 = rstart[n + 1];
        float2 ps = pi[n];           // self loop
        float ax = ps.x, ay = ps.y;
        int j = r0;
        for (; j + 4 <= r1; j += 4) {
            int i0 = part[j], i1 = part[j + 1], i2 = part[j + 2], i3 = part[j + 3];
            float2 a0 = pi[i0], a1 = pi[i1], a2 = pi[i2], a3 = pi[i3];
            ax += a0.x + a1.x + a2.x + a3.x;
            ay += a0.y + a1.y + a2.y + a3.y;
        }
        for (; j < r1; j++) {
            float2 a0 = pi[part[j]];
            ax += a0.x; ay += a0.y;
        }
        float d = dinv[n];
        float s0 = d * ax, s1 = d * ay;
        float u0 = sbe[0], u1 = sbe[1], u2 = sbe[2], u3 = sbe[3];
        float v0 = 0.f, v1 = 0.f, v2 = 0.f, v3 = 0.f;
        float w0 = 0.f, w1 = 0.f;
        #pragma unroll
        for (int jj = 0; jj < 16; jj++) {
            float hj = fmaf(s0, sW1[jj], fmaf(s1, sW1[16 + jj], sb1[jj]));
            u0 = fmaf(hj, sWr[4 * jj + 0], u0);
            u1 = fmaf(hj, sWr[4 * jj + 1], u1);
            u2 = fmaf(hj, sWr[4 * jj + 2], u2);
            u3 = fmaf(hj, sWr[4 * jj + 3], u3);
            v0 = fmaf(hj, sWc[4 * jj + 0], v0);
            v1 = fmaf(hj, sWc[4 * jj + 1], v1);
            v2 = fmaf(hj, sWc[4 * jj + 2], v2);
            v3 = fmaf(hj, sWc[4 * jj + 3], v3);
            w0 = fmaf(hj, sW2[2 * jj], w0);
            w1 = fmaf(hj, sW2[2 * jj + 1], w1);
        }
        U[n] = make_float4(u0, u1, u2, u3);
        V[n] = make_float4(v0, v1, v2, v3);
        qv[n] = make_float2(w0 * d, w1 * d);
    }
}

// ---- edge MLP: 2 edges per thread, pure streaming
__global__ void k_edge(const int* __restrict__ row, const int* __restrict__ col,
                       const float* __restrict__ ea, const float4* __restrict__ U,
                       const float4* __restrict__ V, const float* __restrict__ We,
                       float4* __restrict__ eout, int E) {
    __shared__ float sW16[4];
    int t = threadIdx.x;
    if (t < 4) sW16[t] = We[64 + t];
    __syncthreads();
    int i = blockIdx.x * BLK + t;
    int e = i * 2;
    if (e + 1 < E) {
        int2 rr = ((const int2*)row)[i];
        int2 cc = ((const int2*)col)[i];
        float2 aa = ((const float2*)ea)[i];
        float4 u0 = U[rr.x], u1 = U[rr.y];
        float4 v0 = V[cc.x], v1 = V[cc.y];
        {
            float a0 = u0.x + fmaf(aa.x, sW16[0], v0.x);
            float a1 = u0.y + fmaf(aa.x, sW16[1], v0.y);
            float a2 = u0.z + fmaf(aa.x, sW16[2], v0.z);
            float a3 = u0.w + fmaf(aa.x, sW16[3], v0.w);
            a0 = fmaxf(a0, 0.f); a1 = fmaxf(a1, 0.f);
            a2 = fmaxf(a2, 0.f); a3 = fmaxf(a3, 0.f);
            float m = fmaxf(fmaxf(a0, a1), fmaxf(a2, a3));
            float sum = expf(a0 - m) + expf(a1 - m) + expf(a2 - m) + expf(a3 - m);
            float l = m + logf(sum);
            eout[e] = make_float4(a0 - l, a1 - l, a2 - l, a3 - l);
        }
        {
            float a0 = u1.x + fmaf(aa.y, sW16[0], v1.x);
            float a1 = u1.y + fmaf(aa.y, sW16[1], v1.y);
            float a2 = u1.z + fmaf(aa.y, sW16[2], v1.z);
            float a3 = u1.w + fmaf(aa.y, sW16[3], v1.w);
            a0 = fmaxf(a0, 0.f); a1 = fmaxf(a1, 0.f);
            a2 = fmaxf(a2, 0.f); a3 = fmaxf(a3, 0.f);
            float m = fmaxf(fmaxf(a0, a1), fmaxf(a2, a3));
            float sum = expf(a0 - m) + expf(a1 - m) + expf(a2 - m) + expf(a3 - m);
            float l = m + logf(sum);
            eout[e + 1] = make_float4(a0 - l, a1 - l, a2 - l, a3 - l);
        }
    } else if (e < E) {
        int r = row[e], c = col[e];
        float av = ea[e];
        float4 u = U[r], v = V[c];
        float a0 = u.x + fmaf(av, sW16[0], v.x);
        float a1 = u.y + fmaf(av, sW16[1], v.y);
        float a2 = u.z + fmaf(av, sW16[2], v.z);
        float a3 = u.w + fmaf(av, sW16[3], v.w);
        a0 = fmaxf(a0, 0.f); a1 = fmaxf(a1, 0.f);
        a2 = fmaxf(a2, 0.f); a3 = fmaxf(a3, 0.f);
        float m = fmaxf(fmaxf(a0, a1), fmaxf(a2, a3));
        float sum = expf(a0 - m) + expf(a1 - m) + expf(a2 - m) + expf(a3 - m);
        float l = m + logf(sum);
        eout[e] = make_float4(a0 - l, a1 - l, a2 - l, a3 - l);
    }
}

// ---- conv2 aggregate: thread-per-node register sum -> node log_softmax
__global__ void k_aggC(const unsigned* __restrict__ part, const int* __restrict__ rstart,
                       const float* __restrict__ dinv, const float2* __restrict__ qv,
                       const float* __restrict__ b2, float2* __restrict__ outn, int N) {
    int t = threadIdx.x;
    int n = blockIdx.x * BLK + t;
    if (n < N) {
        int r0 = rstart[n], r1 = rstart[n + 1];
        float2 qs = qv[n];           // self loop
        float bx = qs.x, by = qs.y;
        int j = r0;
        for (; j + 4 <= r1; j += 4) {
            int i0 = part[j], i1 = part[j + 1], i2 = part[j + 2], i3 = part[j + 3];
            float2 a0 = qv[i0], a1 = qv[i1], a2 = qv[i2], a3 = qv[i3];
            bx += a0.x + a1.x + a2.x + a3.x;
            by += a0.y + a1.y + a2.y + a3.y;
        }
        for (; j < r1; j++) {
            float2 a0 = qv[part[j]];
            bx += a0.x; by += a0.y;
        }
        float d = dinv[n];
        float o0 = fmaf(d, bx, b2[0]);
        float o1 = fmaf(d, by, b2[1]);
        float m = fmaxf(o0, o1);
        float l = m + logf(expf(o0 - m) + expf(o1 - m));
        outn[n] = make_float2(o0 - l, o1 - l);
    }
}

extern "C" void kernel_launch(void* const* d_in, const int* in_sizes, int n_in,
                              void* d_out, int out_size, void* d_ws, size_t ws_size,
                              hipStream_t stream) {
    const float* x  = (const float*)d_in[0];
    const int*   ei = (const int*)d_in[1];
    const float* ea = (const float*)d_in[2];
    const float* W1 = (const float*)d_in[3];
    const float* b1 = (const float*)d_in[4];
    const float* We = (const float*)d_in[5];
    const float* be = (const float*)d_in[6];
    const float* W2 = (const float*)d_in[7];
    const float* b2 = (const float*)d_in[8];

    const int N = in_sizes[0] / 2;       // 100000
    const int E = in_sizes[2];           // 3200000
    const int* row = ei;
    const int* col = ei + E;
    const int NSB = (N + SBS - 1) >> SBH;   // 196 super-buckets
    const int NCH = (E + CH - 1) / CH;      // 1563 chunks

    float2* out_nodes = (float2*)d_out;                           // [N,2]
    float4* out_edges = (float4*)((float*)d_out + 2 * (size_t)N); // [E,4]

    // ws layout (bytes), total ~20.0 MB (ws >= 24.8 MB established in R8):
    char* ws = (char*)d_ws;
    int*      gcount = (int*)    (ws + 0);         // NSBMAX*4
    int*      sbase  = (int*)    (ws + 4096);      // (NSBMAX+1)*4
    float*    dinv   = (float*)  (ws + 16384);     // N*4
    int*      rstart = (int*)    (ws + 416384);    // (N+1)*4
    float2*   pi     = (float2*) (ws + 816640);    // N*8
    float2*   qv     = (float2*) (ws + 1616640);   // N*8
    float4*   U      = (float4*) (ws + 2416640);   // N*16
    float4*   V      = (float4*) (ws + 4016640);   // N*16
    unsigned* part   = (unsigned*)(ws + 5616640);  // E*4 = 12.8 MB
    int*      ccnt   = (int*)    (ws + 18416640);  // NCH*NSBMAX*4 = 1.6 MB

    k_hist <<<NCH, BLK, 0, stream>>>(col, ccnt, E, NSB);
    k_scanA<<<NSB, BLK, 0, stream>>>(ccnt, gcount, NCH);
    k_scanB<<<1,   BLK, 0, stream>>>(gcount, sbase, rstart, NSB, N, E);
    k_part <<<NCH, BLK, 0, stream>>>(row, col, ccnt, sbase, part, E, NSB);
    k_sort <<<NSB, SBS, 0, stream>>>(part, sbase, (const float2*)x, dinv, pi, rstart, N);
    k_aggB <<<(N + BLK - 1) / BLK, BLK, 0, stream>>>(part, rstart, dinv, pi,
                                                     W1, b1, W2, We, be, U, V, qv, N);
    k_edge <<<((E + 1) / 2 + BLK - 1) / BLK, BLK, 0, stream>>>(row, col, ea, U, V, We,
                                                               out_edges, E);
    k_aggC <<<(N + BLK - 1) / BLK, BLK, 0, stream>>>(part, rstart, dinv, qv, b2,
                                                     out_nodes, N);
}

// Round 10
// 251.726 us; speedup vs baseline: 1.1156x; 1.0827x over previous
//
#include <hip/hip_runtime.h>

// GCN 2-layer + edge MLP for SimpleModel_59545426592235.
// R10: R9 + k_part goes back to LDS-staged coalesced flushes (R6-style) but
// at 196 super-buckets / CH=4096: staging arrays are ~30KB (vs R6's 73KB),
// so occupancy is fine, and runs avg 21 edges flushed contiguously -> kills
// the 5-7x scattered-store write-amp measured in R7-R9 (WRITE 67-93MB for a
// 12.8MB payload). Exact deterministic output bases from the ccnt scan
// (zero global atomics). Sort-based aggregation (no atomics) as in R9.

#define BLK 256
#define CH 4096            // edges per chunk
#define SBH 9              // 512 nodes per super-bucket
#define SBS 512
#define NSBMAX 256         // max super-buckets (N <= 131072)
#define NCHMAX 1024        // max chunks (E <= 4.19M at CH=4096)
#define CAP 20480          // k_sort LDS segment capacity (words)

// ---- per-chunk LDS histogram of super-buckets -> ccnt row
__global__ void k_hist(const int* __restrict__ col, int* __restrict__ ccnt,
                       int E, int NSB) {
    __shared__ int hist[NSBMAX];
    int t = threadIdx.x;
    for (int b = t; b < NSB; b += BLK) hist[b] = 0;
    __syncthreads();
    int e0 = blockIdx.x * CH;
    int cnt = min(CH, E - e0);
    for (int k = t; k < cnt; k += BLK)
        atomicAdd(&hist[col[e0 + k] >> SBH], 1);
    __syncthreads();
    int* crow = ccnt + (size_t)blockIdx.x * NSBMAX;
    for (int b = t; b < NSB; b += BLK) crow[b] = hist[b];
}

// ---- column-wise exclusive scan of ccnt in place; totals -> gcount
__global__ void k_scanA(int* __restrict__ ccnt, int* __restrict__ gcount, int NCH) {
    __shared__ int sa[NCHMAX], sb[NCHMAX];
    int s = blockIdx.x, t = threadIdx.x;
    for (int i = t; i < NCHMAX; i += BLK)
        sa[i] = (i < NCH) ? ccnt[(size_t)i * NSBMAX + s] : 0;
    __syncthreads();
    int *src = sa, *dst = sb;
    for (int off = 1; off < NCHMAX; off <<= 1) {
        for (int i = t; i < NCHMAX; i += BLK)
            dst[i] = src[i] + ((i >= off) ? src[i - off] : 0);
        __syncthreads();
        int* tmp = src; src = dst; dst = tmp;
    }
    for (int i = t; i < NCH; i += BLK)
        ccnt[(size_t)i * NSBMAX + s] = (i > 0) ? src[i - 1] : 0;
    if (t == 0) gcount[s] = src[NCH - 1];
}

// ---- exclusive scan of super-bucket totals -> sbase[NSB+1]; rstart[N]=E
__global__ void k_scanB(const int* __restrict__ gcount, int* __restrict__ sbase,
                        int* __restrict__ rstart, int NSB, int N, int E) {
    __shared__ int sa[NSBMAX], sb[NSBMAX];
    int t = threadIdx.x;
    for (int i = t; i < NSBMAX; i += BLK) sa[i] = (i < NSB) ? gcount[i] : 0;
    __syncthreads();
    int *src = sa, *dst = sb;
    for (int off = 1; off < NSBMAX; off <<= 1) {
        for (int i = t; i < NSBMAX; i += BLK)
            dst[i] = src[i] + ((i >= off) ? src[i - off] : 0);
        __syncthreads();
        int* tmp = src; src = dst; dst = tmp;
    }
    for (int i = t; i < NSB; i += BLK)
        sbase[i] = (i > 0) ? src[i - 1] : 0;
    if (t == 0) { sbase[NSB] = src[NSB - 1]; rstart[N] = E; }
}

// ---- partition: exact bases, LDS counting sort, coalesced run flush
__global__ void k_part(const int* __restrict__ row, const int* __restrict__ col,
                       const int* __restrict__ ccnt, const int* __restrict__ sbase,
                       unsigned* __restrict__ part, int E, int NSB) {
    __shared__ int hist[NSBMAX], lstart[NSBMAX], lcur[NSBMAX], gb[NSBMAX];
    __shared__ int sa[NSBMAX];
    __shared__ unsigned sbuf[CH];
    __shared__ unsigned short bid[CH];
    int t = threadIdx.x;
    const int* crow = ccnt + (size_t)blockIdx.x * NSBMAX;
    for (int b = t; b < NSBMAX; b += BLK) {
        gb[b] = (b < NSB) ? (sbase[b] + crow[b]) : 0;
        hist[b] = 0;
    }
    __syncthreads();
    int e0 = blockIdx.x * CH;
    int cnt = min(CH, E - e0);
    for (int k = t; k < cnt; k += BLK)
        atomicAdd(&hist[col[e0 + k] >> SBH], 1);
    __syncthreads();
    // Hillis-Steele inclusive scan over 256 entries (BLK==NSBMAX==256)
    {
        int v = hist[t];
        sa[t] = v;
        __syncthreads();
        for (int off = 1; off < NSBMAX; off <<= 1) {
            int u = sa[t];
            if (t >= off) u += sa[t - off];
            __syncthreads();
            sa[t] = u;
            __syncthreads();
        }
        int ex = sa[t] - hist[t];
        lstart[t] = ex;
        lcur[t] = ex;
    }
    __syncthreads();
    // place edges grouped by bucket; record bucket id
    for (int k = t; k < cnt; k += BLK) {
        int e = e0 + k;
        int c = col[e];
        int b = c >> SBH;
        int off = atomicAdd(&lcur[b], 1);
        sbuf[off] = ((unsigned)row[e] << SBH) | (unsigned)(c & (SBS - 1));
        bid[off] = (unsigned short)b;
    }
    __syncthreads();
    // flush: contiguous within each run; run positions exact
    for (int j = t; j < cnt; j += BLK) {
        int b = bid[j];
        part[gb[b] + (j - lstart[b])] = sbuf[j];
    }
}

// ---- per-super-bucket: full sort by local node (in LDS, in place in part),
//      plus deg -> dinv, pi = x*dinv, rstart
__global__ void __launch_bounds__(SBS) k_sort(unsigned* __restrict__ part,
                        const int* __restrict__ sbase, const float2* __restrict__ x2,
                        float* __restrict__ dinv, float2* __restrict__ pi,
                        int* __restrict__ rstart, int N) {
    __shared__ unsigned sbuf[CAP];
    __shared__ int cnt[SBS], sc[SBS], cur[SBS];
    int s = blockIdx.x, t = threadIdx.x;
    int j0 = sbase[s], j1 = sbase[s + 1];
    int m = j1 - j0;
    if (m > CAP) m = CAP;   // safety clamp (statistically unreachable)
    for (int k = t; k < m; k += SBS) sbuf[k] = part[j0 + k];
    cnt[t] = 0;
    __syncthreads();
    for (int k = t; k < m; k += SBS)
        atomicAdd(&cnt[sbuf[k] & (SBS - 1)], 1);
    __syncthreads();
    sc[t] = cnt[t];
    __syncthreads();
    for (int off = 1; off < SBS; off <<= 1) {
        int v = sc[t];
        if (t >= off) v += sc[t - off];
        __syncthreads();
        sc[t] = v;
        __syncthreads();
    }
    int ex = sc[t] - cnt[t];
    cur[t] = ex;
    int node = (s << SBH) + t;
    if (node < N) {
        int dg = cnt[t];
        float d = rsqrtf((float)(dg + 1));   // +1 self loop
        dinv[node] = d;
        float2 xv = x2[node];
        pi[node] = make_float2(xv.x * d, xv.y * d);
        rstart[node] = j0 + ex;
    }
    __syncthreads();
    for (int k = t; k < m; k += SBS) {
        unsigned w = sbuf[k];
        int dst = atomicAdd(&cur[w & (SBS - 1)], 1);
        part[j0 + dst] = w >> SBH;   // row id, node-sorted
    }
}

// ---- conv1 aggregate: thread-per-node register sum over its run -> U,V,qv
__global__ void k_aggB(const unsigned* __restrict__ part, const int* __restrict__ rstart,
                       const float* __restrict__ dinv, const float2* __restrict__ pi,
                       const float* __restrict__ W1, const float* __restrict__ b1,
                       const float* __restrict__ W2, const float* __restrict__ We,
                       const float* __restrict__ be,
                       float4* __restrict__ U, float4* __restrict__ V,
                       float2* __restrict__ qv, int N) {
    __shared__ float sW1[32], sb1[16], sW2[32], sWr[64], sWc[64], sbe[4];
    int t = threadIdx.x;
    if (t < 32) sW1[t] = W1[t];
    else if (t < 64) sW2[t - 32] = W2[t - 32];
    else if (t < 80) sb1[t - 64] = b1[t - 64];
    else if (t < 144) sWr[t - 80] = We[t - 80];          // We rows 0..15
    else if (t < 208) sWc[t - 144] = We[68 + (t - 144)]; // We rows 17..32
    else if (t < 212) sbe[t - 208] = be[t - 208];
    __syncthreads();
    int n = blockIdx.x * BLK + t;
    if (n < N) {
        int r0 = rstart[n], r1 = rstart[n + 1];
        float2 ps = pi[n];           // self loop
        float ax = ps.x, ay = ps.y;
        int j = r0;
        for (; j + 4 <= r1; j += 4) {
            int i0 = part[j], i1 = part[j + 1], i2 = part[j + 2], i3 = part[j + 3];
            float2 a0 = pi[i0], a1 = pi[i1], a2 = pi[i2], a3 = pi[i3];
            ax += a0.x + a1.x + a2.x + a3.x;
            ay += a0.y + a1.y + a2.y + a3.y;
        }
        for (; j < r1; j++) {
            float2 a0 = pi[part[j]];
            ax += a0.x; ay += a0.y;
        }
        float d = dinv[n];
        float s0 = d * ax, s1 = d * ay;
        float u0 = sbe[0], u1 = sbe[1], u2 = sbe[2], u3 = sbe[3];
        float v0 = 0.f, v1 = 0.f, v2 = 0.f, v3 = 0.f;
        float w0 = 0.f, w1 = 0.f;
        #pragma unroll
        for (int jj = 0; jj < 16; jj++) {
            float hj = fmaf(s0, sW1[jj], fmaf(s1, sW1[16 + jj], sb1[jj]));
            u0 = fmaf(hj, sWr[4 * jj + 0], u0);
            u1 = fmaf(hj, sWr[4 * jj + 1], u1);
            u2 = fmaf(hj, sWr[4 * jj + 2], u2);
            u3 = fmaf(hj, sWr[4 * jj + 3], u3);
            v0 = fmaf(hj, sWc[4 * jj + 0], v0);
            v1 = fmaf(hj, sWc[4 * jj + 1], v1);
            v2 = fmaf(hj, sWc[4 * jj + 2], v2);
            v3 = fmaf(hj, sWc[4 * jj + 3], v3);
            w0 = fmaf(hj, sW2[2 * jj], w0);
            w1 = fmaf(hj, sW2[2 * jj + 1], w1);
        }
        U[n] = make_float4(u0, u1, u2, u3);
        V[n] = make_float4(v0, v1, v2, v3);
        qv[n] = make_float2(w0 * d, w1 * d);
    }
}

// ---- edge MLP: 2 edges per thread, pure streaming
__global__ void k_edge(const int* __restrict__ row, const int* __restrict__ col,
                       const float* __restrict__ ea, const float4* __restrict__ U,
                       const float4* __restrict__ V, const float* __restrict__ We,
                       float4* __restrict__ eout, int E) {
    __shared__ float sW16[4];
    int t = threadIdx.x;
    if (t < 4) sW16[t] = We[64 + t];
    __syncthreads();
    int i = blockIdx.x * BLK + t;
    int e = i * 2;
    if (e + 1 < E) {
        int2 rr = ((const int2*)row)[i];
        int2 cc = ((const int2*)col)[i];
        float2 aa = ((const float2*)ea)[i];
        float4 u0 = U[rr.x], u1 = U[rr.y];
        float4 v0 = V[cc.x], v1 = V[cc.y];
        {
            float a0 = u0.x + fmaf(aa.x, sW16[0], v0.x);
            float a1 = u0.y + fmaf(aa.x, sW16[1], v0.y);
            float a2 = u0.z + fmaf(aa.x, sW16[2], v0.z);
            float a3 = u0.w + fmaf(aa.x, sW16[3], v0.w);
            a0 = fmaxf(a0, 0.f); a1 = fmaxf(a1, 0.f);
            a2 = fmaxf(a2, 0.f); a3 = fmaxf(a3, 0.f);
            float m = fmaxf(fmaxf(a0, a1), fmaxf(a2, a3));
            float sum = expf(a0 - m) + expf(a1 - m) + expf(a2 - m) + expf(a3 - m);
            float l = m + logf(sum);
            eout[e] = make_float4(a0 - l, a1 - l, a2 - l, a3 - l);
        }
        {
            float a0 = u1.x + fmaf(aa.y, sW16[0], v1.x);
            float a1 = u1.y + fmaf(aa.y, sW16[1], v1.y);
            float a2 = u1.z + fmaf(aa.y, sW16[2], v1.z);
            float a3 = u1.w + fmaf(aa.y, sW16[3], v1.w);
            a0 = fmaxf(a0, 0.f); a1 = fmaxf(a1, 0.f);
            a2 = fmaxf(a2, 0.f); a3 = fmaxf(a3, 0.f);
            float m = fmaxf(fmaxf(a0, a1), fmaxf(a2, a3));
            float sum = expf(a0 - m) + expf(a1 - m) + expf(a2 - m) + expf(a3 - m);
            float l = m + logf(sum);
            eout[e + 1] = make_float4(a0 - l, a1 - l, a2 - l, a3 - l);
        }
    } else if (e < E) {
        int r = row[e], c = col[e];
        float av = ea[e];
        float4 u = U[r], v = V[c];
        float a0 = u.x + fmaf(av, sW16[0], v.x);
        float a1 = u.y + fmaf(av, sW16[1], v.y);
        float a2 = u.z + fmaf(av, sW16[2], v.z);
        float a3 = u.w + fmaf(av, sW16[3], v.w);
        a0 = fmaxf(a0, 0.f); a1 = fmaxf(a1, 0.f);
        a2 = fmaxf(a2, 0.f); a3 = fmaxf(a3, 0.f);
        float m = fmaxf(fmaxf(a0, a1), fmaxf(a2, a3));
        float sum = expf(a0 - m) + expf(a1 - m) + expf(a2 - m) + expf(a3 - m);
        float l = m + logf(sum);
        eout[e] = make_float4(a0 - l, a1 - l, a2 - l, a3 - l);
    }
}

// ---- conv2 aggregate: thread-per-node register sum -> node log_softmax
__global__ void k_aggC(const unsigned* __restrict__ part, const int* __restrict__ rstart,
                       const float* __restrict__ dinv, const float2* __restrict__ qv,
                       const float* __restrict__ b2, float2* __restrict__ outn, int N) {
    int t = threadIdx.x;
    int n = blockIdx.x * BLK + t;
    if (n < N) {
        int r0 = rstart[n], r1 = rstart[n + 1];
        float2 qs = qv[n];           // self loop
        float bx = qs.x, by = qs.y;
        int j = r0;
        for (; j + 4 <= r1; j += 4) {
            int i0 = part[j], i1 = part[j + 1], i2 = part[j + 2], i3 = part[j + 3];
            float2 a0 = qv[i0], a1 = qv[i1], a2 = qv[i2], a3 = qv[i3];
            bx += a0.x + a1.x + a2.x + a3.x;
            by += a0.y + a1.y + a2.y + a3.y;
        }
        for (; j < r1; j++) {
            float2 a0 = qv[part[j]];
            bx += a0.x; by += a0.y;
        }
        float d = dinv[n];
        float o0 = fmaf(d, bx, b2[0]);
        float o1 = fmaf(d, by, b2[1]);
        float m = fmaxf(o0, o1);
        float l = m + logf(expf(o0 - m) + expf(o1 - m));
        outn[n] = make_float2(o0 - l, o1 - l);
    }
}

extern "C" void kernel_launch(void* const* d_in, const int* in_sizes, int n_in,
                              void* d_out, int out_size, void* d_ws, size_t ws_size,
                              hipStream_t stream) {
    const float* x  = (const float*)d_in[0];
    const int*   ei = (const int*)d_in[1];
    const float* ea = (const float*)d_in[2];
    const float* W1 = (const float*)d_in[3];
    const float* b1 = (const float*)d_in[4];
    const float* We = (const float*)d_in[5];
    const float* be = (const float*)d_in[6];
    const float* W2 = (const float*)d_in[7];
    const float* b2 = (const float*)d_in[8];

    const int N = in_sizes[0] / 2;       // 100000
    const int E = in_sizes[2];           // 3200000
    const int* row = ei;
    const int* col = ei + E;
    const int NSB = (N + SBS - 1) >> SBH;   // 196 super-buckets
    const int NCH = (E + CH - 1) / CH;      // 782 chunks

    float2* out_nodes = (float2*)d_out;                           // [N,2]
    float4* out_edges = (float4*)((float*)d_out + 2 * (size_t)N); // [E,4]

    // ws layout (bytes), total ~19.3 MB:
    char* ws = (char*)d_ws;
    int*      gcount = (int*)    (ws + 0);         // NSBMAX*4
    int*      sbase  = (int*)    (ws + 4096);      // (NSBMAX+1)*4
    float*    dinv   = (float*)  (ws + 16384);     // N*4
    int*      rstart = (int*)    (ws + 416384);    // (N+1)*4
    float2*   pi     = (float2*) (ws + 816640);    // N*8
    float2*   qv     = (float2*) (ws + 1616640);   // N*8
    float4*   U      = (float4*) (ws + 2416640);   // N*16
    float4*   V      = (float4*) (ws + 4016640);   // N*16
    unsigned* part   = (unsigned*)(ws + 5616640);  // E*4 = 12.8 MB
    int*      ccnt   = (int*)    (ws + 18416640);  // NCH*NSBMAX*4 = 800 KB

    k_hist <<<NCH, BLK, 0, stream>>>(col, ccnt, E, NSB);
    k_scanA<<<NSB, BLK, 0, stream>>>(ccnt, gcount, NCH);
    k_scanB<<<1,   BLK, 0, stream>>>(gcount, sbase, rstart, NSB, N, E);
    k_part <<<NCH, BLK, 0, stream>>>(row, col, ccnt, sbase, part, E, NSB);
    k_sort <<<NSB, SBS, 0, stream>>>(part, sbase, (const float2*)x, dinv, pi, rstart, N);
    k_aggB <<<(N + BLK - 1) / BLK, BLK, 0, stream>>>(part, rstart, dinv, pi,
                                                     W1, b1, W2, We, be, U, V, qv, N);
    k_edge <<<((E + 1) / 2 + BLK - 1) / BLK, BLK, 0, stream>>>(row, col, ea, U, V, We,
                                                               out_edges, E);
    k_aggC <<<(N + BLK - 1) / BLK, BLK, 0, stream>>>(part, rstart, dinv, qv, b2,
                                                     out_nodes, N);
}